// Round 11
// baseline (248.112 us; speedup 1.0000x reference)
//
#include <hip/hip_runtime.h>
#include <cstdint>
#include <cstddef>

// Problem constants (N=2, C=128, Ce=64, H=W=96)
#define HW_ 9216
#define CC 128
#define NQT 144      // HW/64 p-tiles (conv)
#define NQT4 36      // HW/256 q-tiles (attn: 256 q per block, 64 per wave)
#define LOG2E 1.44269504088896f

typedef short bf16x8 __attribute__((ext_vector_type(8)));
typedef unsigned short u16x4 __attribute__((ext_vector_type(4)));
typedef unsigned short u16x8 __attribute__((ext_vector_type(8)));
typedef float f32x4 __attribute__((ext_vector_type(4)));

__device__ __forceinline__ unsigned short f2bf(float f) {
    unsigned int u = __builtin_bit_cast(unsigned int, f);
    u += 0x7FFFu + ((u >> 16) & 1u);   // RNE
    return (unsigned short)(u >> 16);
}

__device__ __forceinline__ float fast_exp2(float x) {
#if __has_builtin(__builtin_amdgcn_exp2f)
    return __builtin_amdgcn_exp2f(x);   // bare v_exp_f32
#else
    return exp2f(x);
#endif
}

__device__ __forceinline__ unsigned int cvt_pk_bf16(float lo, float hi) {
    unsigned int r;
    asm("v_cvt_pk_bf16_f32 %0, %1, %2" : "=v"(r) : "v"(lo), "v"(hi));
    return r;
}

// ---------------------------------------------------------------------------
// Kernel 1: transpose weights into wt[c][o], o in [0,256): 0..63=w1, 64..127=w2,
// 128..255=wa.
// ---------------------------------------------------------------------------
__global__ __launch_bounds__(256) void prep_w(const float* __restrict__ w1,
                                              const float* __restrict__ w2,
                                              const float* __restrict__ wa,
                                              float* __restrict__ wt) {
    int idx = blockIdx.x * 256 + threadIdx.x;   // 32768 total
    int o = idx >> 7, c = idx & 127;
    float v;
    if (o < 64)       v = w1[o * 128 + c];
    else if (o < 128) v = w2[(o - 64) * 128 + c];
    else              v = wa[(o - 128) * 128 + c];
    wt[c * 256 + o] = v;
}

// ---------------------------------------------------------------------------
// Kernel 2: 1x1 conv + PReLU (fp32 accumulate), write bf16.
//   oset 0 -> Q[n][p][d] (pre-scaled by log2e; PReLU commutes with pos scale)
//   oset 1 -> K[n][p][d]
//   oset 2,3 -> Vt[n][c][p]
// ---------------------------------------------------------------------------
__global__ __launch_bounds__(256) void conv_kernel(
    const float* __restrict__ x, const float* __restrict__ wt,
    const float* __restrict__ b1, const float* __restrict__ a1,
    const float* __restrict__ b2, const float* __restrict__ a2,
    const float* __restrict__ ba, const float* __restrict__ aa,
    unsigned short* __restrict__ qb, unsigned short* __restrict__ kb,
    unsigned short* __restrict__ vtb) {
    const int ptile = blockIdx.x;   // 144
    const int oset  = blockIdx.y;   // 4
    const int n     = blockIdx.z;   // 2
    const int t = threadIdx.x;
    const int p = t & 63;
    const int og = __builtin_amdgcn_readfirstlane(t >> 6);
    const int p0 = ptile * 64;

    __shared__ float xs[128 * 64];
    for (int c = t >> 6; c < 128; c += 4)
        xs[c * 64 + p] = x[((size_t)n * CC + c) * HW_ + p0 + p];
    __syncthreads();

    const int obase = oset * 64 + og * 16;
    float acc[16];
#pragma unroll
    for (int i = 0; i < 16; i++) acc[i] = 0.f;

    for (int c = 0; c < 128; c++) {
        float xv = xs[c * 64 + p];
        const float* wr = wt + c * 256 + obase;   // uniform -> s_load
#pragma unroll
        for (int i = 0; i < 16; i++) acc[i] = fmaf(wr[i], xv, acc[i]);
    }

    const float* bias_p;
    const float* slope_p;
    if (oset == 0)      { bias_p = b1; slope_p = a1; }
    else if (oset == 1) { bias_p = b2; slope_p = a2; }
    else                { bias_p = ba; slope_p = aa; }
    const float slope = slope_p[0];

    unsigned short vals[16];
#pragma unroll
    for (int i = 0; i < 16; i++) {
        float bv = (oset < 2) ? bias_p[og * 16 + i] : bias_p[obase - 128 + i];
        float y = acc[i] + bv;
        y = (y >= 0.f) ? y : slope * y;
        if (oset == 0) y *= LOG2E;   // fold softmax's ln->log2 into Q
        vals[i] = f2bf(y);
    }

    if (oset < 2) {
        unsigned short* dst = (oset == 0 ? qb : kb) + ((size_t)n * HW_ + p0 + p) * 64 + og * 16;
        bf16x8 v0, v1;
#pragma unroll
        for (int i = 0; i < 8; i++) { v0[i] = (short)vals[i]; v1[i] = (short)vals[8 + i]; }
        *(bf16x8*)(dst)     = v0;
        *(bf16x8*)(dst + 8) = v1;
    } else {
        int c0 = obase - 128;
#pragma unroll
        for (int i = 0; i < 16; i++)
            vtb[((size_t)n * CC + c0 + i) * HW_ + p0 + p] = vals[i];
    }
}

// ---------------------------------------------------------------------------
// Kernel 3: flash attention, S^T formulation, NO-MAX softmax, 64 q PER WAVE.
//   R10 falsified load-imbalance; accounting shows the LDS pipe at ~65-73%
//   utilization is the binding resource (38 KB/wave-iter for 32 q). Because
//   no-max softmax has NO cross-tile dependency (P = exp2(S) elementwise,
//   l is a plain sum), q-per-wave can grow without growing live S state:
//   process S per (sub, ct) 16x16 tile with only 16 s-regs live.
//   4 subs x 16 q = 64 q/wave: each K A-read feeds 8 QK MFMAs, each V A-read
//   feeds 8 PV MFMAs -> 46 KB/wave-iter for 64 q (-39% LDS traffic vs R6).
//   S^T = K·Q^T  (A=K, B=Q)  -> C/D: col = q = lane&15, row = j = quad*4+r
//   P^T staged per (wave, sub) in 1KB p_lds slots, all 16 (sub,ct) writes,
//   one fence, then 8 bp reads, one fence (2 fences/iter vs R6's 4).
//   O^T = V^T·P^T (A=V^T, B=P^T) -> col = q, row = c-local
// Block = 4 waves x 64 q = 256 q. KV chunked over blockIdx.y.
// launch_bounds(256,1): no forced VGPR cap (R7 spill lesson); est ~250 VGPR.
// ---------------------------------------------------------------------------
__global__ __launch_bounds__(256, 1) void attn_kernel(
    const unsigned short* __restrict__ qb, const unsigned short* __restrict__ kb,
    const unsigned short* __restrict__ vtb,
    float* __restrict__ o_part, float* __restrict__ l_part,
    int nch, int chunk_j) {
    const int qt    = blockIdx.x;   // 36
    const int chunk = blockIdx.y;   // nch
    const int n     = blockIdx.z;   // 2
    const int t = threadIdx.x;
    const int w = t >> 6;
    const int lane = t & 63;
    const int l15 = lane & 15;
    const int quad = lane >> 4;
    const int e7 = l15 & 7;

    __shared__ __align__(16) unsigned short k_lds[64 * 64];    // [j][d] swizzled, 8 KB
    __shared__ __align__(16) unsigned short v_lds[128 * 64];   // [c][j] swizzled, 16 KB
    __shared__ __align__(16) unsigned short p_lds[4 * 4 * 1024]; // [wave][sub][q][j], 16 KB

    // Q B-fragments for the four 16-q subs: lane holds q=l15, d = quad*8..
    bf16x8 bq0[4], bq1[4];
#pragma unroll
    for (int s = 0; s < 4; s++) {
        const int row_g = qt * 256 + w * 64 + s * 16 + l15;
        bq0[s] = *(const bf16x8*)(qb + ((size_t)n * HW_ + row_g) * 64 + quad * 8);
        bq1[s] = *(const bf16x8*)(qb + ((size_t)n * HW_ + row_g) * 64 + 32 + quad * 8);
    }

    f32x4 acc_o[4][8];
#pragma unroll
    for (int s = 0; s < 4; s++)
#pragma unroll
        for (int i = 0; i < 8; i++) acc_o[s][i] = (f32x4){0.f, 0.f, 0.f, 0.f};
    float l_s[4] = {0.f, 0.f, 0.f, 0.f};   // in-lane partial of l(q) per sub

    const int stg_row = t >> 3, stg_seg = t & 7;
    const int iters = chunk_j / 64;
    int j0 = chunk * chunk_j;

    // software pipeline: prefetch tile 0 into VGPRs
    bf16x8 kr0, kr1, vr0, vr1, vr2, vr3;
    {
        const unsigned short* kp = kb + ((size_t)n * HW_ + j0 + stg_row) * 64 + stg_seg * 8;
        kr0 = *(const bf16x8*)kp;
        kr1 = *(const bf16x8*)(kp + 32 * 64);
        const unsigned short* vp = vtb + ((size_t)n * CC + stg_row) * HW_ + j0 + stg_seg * 8;
        vr0 = *(const bf16x8*)vp;
        vr1 = *(const bf16x8*)(vp + (size_t)32 * HW_);
        vr2 = *(const bf16x8*)(vp + (size_t)64 * HW_);
        vr3 = *(const bf16x8*)(vp + (size_t)96 * HW_);
    }

    for (int it = 0; it < iters; ++it, j0 += 64) {
        __syncthreads();   // previous iteration's k/v_lds reads complete
        {
            int r0 = stg_row, r1 = stg_row + 32;
            *(bf16x8*)&k_lds[r0 * 64 + ((stg_seg ^ (r0 & 7)) * 8)] = kr0;
            *(bf16x8*)&k_lds[r1 * 64 + ((stg_seg ^ (r1 & 7)) * 8)] = kr1;
            *(bf16x8*)&v_lds[r0 * 64 + ((stg_seg ^ (r0 & 7)) * 8)] = vr0;
            *(bf16x8*)&v_lds[r1 * 64 + ((stg_seg ^ (r1 & 7)) * 8)] = vr1;
            int r2 = stg_row + 64, r3 = stg_row + 96;
            *(bf16x8*)&v_lds[r2 * 64 + ((stg_seg ^ (r2 & 7)) * 8)] = vr2;
            *(bf16x8*)&v_lds[r3 * 64 + ((stg_seg ^ (r3 & 7)) * 8)] = vr3;
        }
        __syncthreads();

        if (it + 1 < iters) {   // issue next tile's loads; overlap with compute
            const unsigned short* kp = kb + ((size_t)n * HW_ + j0 + 64 + stg_row) * 64 + stg_seg * 8;
            kr0 = *(const bf16x8*)kp;
            kr1 = *(const bf16x8*)(kp + 32 * 64);
            const unsigned short* vp = vtb + ((size_t)n * CC + stg_row) * HW_ + j0 + 64 + stg_seg * 8;
            vr0 = *(const bf16x8*)vp;
            vr1 = *(const bf16x8*)(vp + (size_t)32 * HW_);
            vr2 = *(const bf16x8*)(vp + (size_t)64 * HW_);
            vr3 = *(const bf16x8*)(vp + (size_t)96 * HW_);
        }

        // QK^T + per-tile softmax + P staging: ct outer (share ak across subs),
        // sub inner. Only one 16x16 S tile (4 regs) live per (sub,ct).
#pragma unroll
        for (int ct = 0; ct < 4; ct++) {
            int jr = ct * 16 + l15;
            bf16x8 ak0 = *(const bf16x8*)&k_lds[jr * 64 + ((quad ^ e7) * 8)];
            bf16x8 ak1 = *(const bf16x8*)&k_lds[jr * 64 + (((4 + quad) ^ e7) * 8)];
            const int chunkid = 2 * ct + (quad >> 1);
            const int off = l15 * 64 + ((chunkid ^ e7) * 8) + 4 * (quad & 1);
#pragma unroll
            for (int s = 0; s < 4; s++) {
                f32x4 z = (f32x4){0.f, 0.f, 0.f, 0.f};
                z = __builtin_amdgcn_mfma_f32_16x16x32_bf16(ak0, bq0[s], z, 0, 0, 0);
                z = __builtin_amdgcn_mfma_f32_16x16x32_bf16(ak1, bq1[s], z, 0, 0, 0);
                // P = exp2(S) raw (no max: softmax shift-invariance, S bounded)
                float p0 = fast_exp2(z[0]);
                float p1 = fast_exp2(z[1]);
                float p2 = fast_exp2(z[2]);
                float p3 = fast_exp2(z[3]);
                l_s[s] += (p0 + p1) + (p2 + p3);
                uint2 tmp;
                tmp.x = cvt_pk_bf16(p0, p1);
                tmp.y = cvt_pk_bf16(p2, p3);
                *(u16x4*)&p_lds[(w * 4 + s) * 1024 + off] = __builtin_bit_cast(u16x4, tmp);
            }
        }

        asm volatile("" ::: "memory");   // all P writes before any P readback

        bf16x8 bp0[4], bp1[4];
#pragma unroll
        for (int s = 0; s < 4; s++) {
            bp0[s] = __builtin_bit_cast(bf16x8,
                *(const u16x8*)&p_lds[(w * 4 + s) * 1024 + l15 * 64 + ((quad ^ e7) * 8)]);
            bp1[s] = __builtin_bit_cast(bf16x8,
                *(const u16x8*)&p_lds[(w * 4 + s) * 1024 + l15 * 64 + (((4 + quad) ^ e7) * 8)]);
        }
        asm volatile("" ::: "memory");   // P reads before next iter's writes

        // O^T += V^T P^T : each V A-read feeds all 4 subs (8 MFMAs)
        __builtin_amdgcn_s_setprio(1);
#pragma unroll
        for (int ctv = 0; ctv < 8; ctv++) {
            int cr = ctv * 16 + l15;
            bf16x8 av0 = *(const bf16x8*)&v_lds[cr * 64 + ((quad ^ e7) * 8)];
            bf16x8 av1 = *(const bf16x8*)&v_lds[cr * 64 + (((4 + quad) ^ e7) * 8)];
#pragma unroll
            for (int s = 0; s < 4; s++) {
                acc_o[s][ctv] = __builtin_amdgcn_mfma_f32_16x16x32_bf16(av0, bp0[s], acc_o[s][ctv], 0, 0, 0);
                acc_o[s][ctv] = __builtin_amdgcn_mfma_f32_16x16x32_bf16(av1, bp1[s], acc_o[s][ctv], 0, 0, 0);
            }
        }
        __builtin_amdgcn_s_setprio(0);
    }

    // epilogue: reduce l across quads (once per kernel, not per iter)
#pragma unroll
    for (int s = 0; s < 4; s++) {
        l_s[s] += __shfl_xor(l_s[s], 16);
        l_s[s] += __shfl_xor(l_s[s], 32);
    }

    // partials: O^T layout [c][q], q in [0,256) per block
    const size_t cbase = ((size_t)(n * NQT4 + qt) * nch + chunk) * 128;
#pragma unroll
    for (int s = 0; s < 4; s++) {
        const int ql = w * 64 + s * 16 + l15;
#pragma unroll
        for (int ctv = 0; ctv < 8; ctv++)
#pragma unroll
            for (int r = 0; r < 4; r++) {
                int c = ctv * 16 + 4 * quad + r;
                o_part[(cbase + c) * 256 + ql] = acc_o[s][ctv][r];
            }
    }
    if (quad == 0) {   // l is quad-uniform per q after the reduce
        size_t lb = ((size_t)(n * NQT4 + qt) * nch + chunk) * 256;
#pragma unroll
        for (int s = 0; s < 4; s++)
            l_part[lb + w * 64 + s * 16 + l15] = l_s[s];
    }
}

// ---------------------------------------------------------------------------
// Kernel 4: combine nch partials (plain sums — no max tracking), normalize,
// write out[n][c][p] fp32.
// Layout: o_part[((nqt*nch+ch)*128 + c)*256 + q], l[(nqt*nch+ch)*256 + q]
// ---------------------------------------------------------------------------
__global__ __launch_bounds__(256) void combine_kernel(
    const float* __restrict__ o_part, const float* __restrict__ lp,
    float* __restrict__ out, int nch) {
    int gid = blockIdx.x * 256 + threadIdx.x;
    int r = gid & 255;             // q within block
    int rest = gid >> 8;
    int c = rest & 127;
    int nqt = rest >> 7;           // 0..71 = n*36 + qtp
    int n = nqt / NQT4, qtp = nqt - n * NQT4;

    float num = 0.f, den = 0.f;
    for (int ch = 0; ch < nch; ch++) {
        num += o_part[(((size_t)nqt * nch + ch) * 128 + c) * 256 + r];
        den += lp[((size_t)nqt * nch + ch) * 256 + r];
    }
    out[((size_t)n * CC + c) * HW_ + qtp * 256 + r] = num / den;
}

// ---------------------------------------------------------------------------
// Workspace layout (bytes):
//   wt 0 (131072) | qb 131072 (2359296) | kb 2490368 (2359296)
//   vtb 4849664 (4718592) | o_part 9568256 (nch*9437184) | l after o_part
// l = nch * 73728 bytes. Ladder: nch 12 (~124 MB) -> 8 (~86) -> 6 (~67)
// -> 4 (~48) -> 2.
// ---------------------------------------------------------------------------
extern "C" void kernel_launch(void* const* d_in, const int* in_sizes, int n_in,
                              void* d_out, int out_size, void* d_ws, size_t ws_size,
                              hipStream_t stream) {
    const float* x  = (const float*)d_in[0];
    const float* w1 = (const float*)d_in[1];
    const float* b1 = (const float*)d_in[2];
    const float* a1 = (const float*)d_in[3];
    const float* w2 = (const float*)d_in[4];
    const float* b2 = (const float*)d_in[5];
    const float* a2 = (const float*)d_in[6];
    const float* wa = (const float*)d_in[7];
    const float* ba = (const float*)d_in[8];
    const float* aa = (const float*)d_in[9];
    float* out = (float*)d_out;

    auto need = [](int nc) -> size_t {
        return 9568256ull + (size_t)nc * 9437184ull + (size_t)nc * 73728ull;
    };
    int nch;
    if (ws_size >= need(12))     nch = 12;   // 864 blocks
    else if (ws_size >= need(8)) nch = 8;
    else if (ws_size >= need(6)) nch = 6;
    else if (ws_size >= need(4)) nch = 4;
    else                         nch = 2;
    const int chunk_j = HW_ / nch;

    char* ws = (char*)d_ws;
    float*          wt     = (float*)(ws + 0);
    unsigned short* qb     = (unsigned short*)(ws + 131072);
    unsigned short* kb     = (unsigned short*)(ws + 2490368);
    unsigned short* vtb    = (unsigned short*)(ws + 4849664);
    float*          o_part = (float*)(ws + 9568256);
    float*          lpart  = (float*)(ws + 9568256 + (size_t)nch * 9437184);

    hipLaunchKernelGGL(prep_w, dim3(128), dim3(256), 0, stream, w1, w2, wa, wt);
    hipLaunchKernelGGL(conv_kernel, dim3(144, 4, 2), dim3(256), 0, stream,
                       x, wt, b1, a1, b2, a2, ba, aa, qb, kb, vtb);
    hipLaunchKernelGGL(attn_kernel, dim3(NQT4, nch, 2), dim3(256), 0, stream,
                       qb, kb, vtb, o_part, lpart, nch, chunk_j);
    hipLaunchKernelGGL(combine_kernel, dim3(2 * NQT4 * 128 * 256 / 256), dim3(256), 0, stream,
                       o_part, lpart, out, nch);
}

// Round 12
// 190.139 us; speedup vs baseline: 1.3049x; 1.3049x over previous
//
#include <hip/hip_runtime.h>
#include <cstdint>
#include <cstddef>

// Problem constants (N=2, C=128, Ce=64, H=W=96)
#define HW_ 9216
#define CC 128
#define NQT 144      // HW/64 p-tiles (conv)
#define NQT2 72      // HW/128 q-tiles (attn: 128 q per block)
#define LOG2E 1.44269504088896f

typedef short bf16x8 __attribute__((ext_vector_type(8)));
typedef unsigned short u16x4 __attribute__((ext_vector_type(4)));
typedef unsigned short u16x8 __attribute__((ext_vector_type(8)));
typedef float f32x4 __attribute__((ext_vector_type(4)));

__device__ __forceinline__ unsigned short f2bf(float f) {
    unsigned int u = __builtin_bit_cast(unsigned int, f);
    u += 0x7FFFu + ((u >> 16) & 1u);   // RNE
    return (unsigned short)(u >> 16);
}

__device__ __forceinline__ float fast_exp2(float x) {
#if __has_builtin(__builtin_amdgcn_exp2f)
    return __builtin_amdgcn_exp2f(x);   // bare v_exp_f32
#else
    return exp2f(x);
#endif
}

__device__ __forceinline__ unsigned int cvt_pk_bf16(float lo, float hi) {
    unsigned int r;
    asm("v_cvt_pk_bf16_f32 %0, %1, %2" : "=v"(r) : "v"(lo), "v"(hi));
    return r;
}

// ---------------------------------------------------------------------------
// Kernel 1: transpose weights into wt[c][o], o in [0,256): 0..63=w1, 64..127=w2,
// 128..255=wa.
// ---------------------------------------------------------------------------
__global__ __launch_bounds__(256) void prep_w(const float* __restrict__ w1,
                                              const float* __restrict__ w2,
                                              const float* __restrict__ wa,
                                              float* __restrict__ wt) {
    int idx = blockIdx.x * 256 + threadIdx.x;   // 32768 total
    int o = idx >> 7, c = idx & 127;
    float v;
    if (o < 64)       v = w1[o * 128 + c];
    else if (o < 128) v = w2[(o - 64) * 128 + c];
    else              v = wa[(o - 128) * 128 + c];
    wt[c * 256 + o] = v;
}

// ---------------------------------------------------------------------------
// Kernel 2: 1x1 conv + PReLU (fp32 accumulate), write bf16.
//   oset 0 -> Q[n][p][d] (pre-scaled by log2e; PReLU commutes with pos scale)
//   oset 1 -> K[n][p][d]
//   oset 2,3 -> Vt[n][c][p]
// R12: inferred ~65-75 us (total minus attn across R5-R10) vs ~8 us floor.
// Suspected serial s_load->FMA dependence per c. Fixes: float4 staging;
// #pragma unroll 8 on the c-loop so 8 independent s_load_dwordx16 issue
// ahead of the FMA block (latency amortized 8x). Values bit-identical.
// ---------------------------------------------------------------------------
__global__ __launch_bounds__(256) void conv_kernel(
    const float* __restrict__ x, const float* __restrict__ wt,
    const float* __restrict__ b1, const float* __restrict__ a1,
    const float* __restrict__ b2, const float* __restrict__ a2,
    const float* __restrict__ ba, const float* __restrict__ aa,
    unsigned short* __restrict__ qb, unsigned short* __restrict__ kb,
    unsigned short* __restrict__ vtb) {
    const int ptile = blockIdx.x;   // 144
    const int oset  = blockIdx.y;   // 4
    const int n     = blockIdx.z;   // 2
    const int t = threadIdx.x;
    const int p = t & 63;
    const int og = __builtin_amdgcn_readfirstlane(t >> 6);
    const int p0 = ptile * 64;

    __shared__ float xs[128 * 64];
    {   // float4 staging: thread t covers rows c = t>>4 step 16, 4 p each
        const int cs = t >> 4, p4 = (t & 15) * 4;
#pragma unroll
        for (int c = cs; c < 128; c += 16) {
            float4 v = *(const float4*)(x + ((size_t)n * CC + c) * HW_ + p0 + p4);
            *(float4*)&xs[c * 64 + p4] = v;
        }
    }
    __syncthreads();

    const int obase = oset * 64 + og * 16;
    float acc[16];
#pragma unroll
    for (int i = 0; i < 16; i++) acc[i] = 0.f;

#pragma unroll 8
    for (int c = 0; c < 128; c++) {
        float xv = xs[c * 64 + p];
        const float* wr = wt + c * 256 + obase;   // uniform -> s_load_dwordx16
#pragma unroll
        for (int i = 0; i < 16; i++) acc[i] = fmaf(wr[i], xv, acc[i]);
    }

    const float* bias_p;
    const float* slope_p;
    if (oset == 0)      { bias_p = b1; slope_p = a1; }
    else if (oset == 1) { bias_p = b2; slope_p = a2; }
    else                { bias_p = ba; slope_p = aa; }
    const float slope = slope_p[0];

    unsigned short vals[16];
#pragma unroll
    for (int i = 0; i < 16; i++) {
        float bv = (oset < 2) ? bias_p[og * 16 + i] : bias_p[obase - 128 + i];
        float y = acc[i] + bv;
        y = (y >= 0.f) ? y : slope * y;
        if (oset == 0) y *= LOG2E;   // fold softmax's ln->log2 into Q
        vals[i] = f2bf(y);
    }

    if (oset < 2) {
        unsigned short* dst = (oset == 0 ? qb : kb) + ((size_t)n * HW_ + p0 + p) * 64 + og * 16;
        bf16x8 v0, v1;
#pragma unroll
        for (int i = 0; i < 8; i++) { v0[i] = (short)vals[i]; v1[i] = (short)vals[8 + i]; }
        *(bf16x8*)(dst)     = v0;
        *(bf16x8*)(dst + 8) = v1;
    } else {
        int c0 = obase - 128;
#pragma unroll
        for (int i = 0; i < 16; i++)
            vtb[((size_t)n * CC + c0 + i) * HW_ + p0 + p] = vals[i];
    }
}

// ---------------------------------------------------------------------------
// Kernel 3: flash attention, S^T formulation, 32 q per wave, NO-MAX softmax.
//   EXACT R6 kernel (proven 94 us attn, best of 7 structural variants:
//   R7 2-wave, R8 2-wave-fixed, R9 L2-direct, R10 nch=12, R11 64q all lost).
//   S^T = K·Q^T  (A=K, B=Q)  -> C/D: col = q = lane&15, row = j = quad*4+r
//   P = exp2(S) raw (softmax shift-invariance; S bounded ~40 in log2 domain)
//   l accumulates in-lane; one 2-shfl reduce at epilogue; combine = plain sums
//   P^T staged per-wave in a 1KB buffer reused by both halves (write-a,
//   read-a, write-b, read-b; per-wave DS ops in-order; fences pin order).
//   O^T = V^T·P^T (A=V^T, B=P^T) -> col = q, row = c-local
// Block = 4 waves x 32 q = 128 q. KV chunked over blockIdx.y.
// ---------------------------------------------------------------------------
__global__ __launch_bounds__(256, 2) void attn_kernel(
    const unsigned short* __restrict__ qb, const unsigned short* __restrict__ kb,
    const unsigned short* __restrict__ vtb,
    float* __restrict__ o_part, float* __restrict__ l_part,
    int nch, int chunk_j) {
    const int qt    = blockIdx.x;   // 72
    const int chunk = blockIdx.y;   // nch
    const int n     = blockIdx.z;   // 2
    const int t = threadIdx.x;
    const int w = t >> 6;
    const int lane = t & 63;
    const int l15 = lane & 15;
    const int quad = lane >> 4;
    const int e7 = l15 & 7;

    __shared__ __align__(16) unsigned short k_lds[64 * 64];   // [j][d] swizzled, 8 KB
    __shared__ __align__(16) unsigned short v_lds[128 * 64];  // [c][j] swizzled, 16 KB
    __shared__ __align__(16) unsigned short p_lds[4 * 1024];  // per-wave [q][j], 8 KB

    // Q B-fragments for the two 16-q halves: lane holds q=l15, d = quad*8..
    const int row_ga = qt * 128 + w * 32 + l15;
    const int row_gb = row_ga + 16;
    const bf16x8 bq0a = *(const bf16x8*)(qb + ((size_t)n * HW_ + row_ga) * 64 + quad * 8);
    const bf16x8 bq1a = *(const bf16x8*)(qb + ((size_t)n * HW_ + row_ga) * 64 + 32 + quad * 8);
    const bf16x8 bq0b = *(const bf16x8*)(qb + ((size_t)n * HW_ + row_gb) * 64 + quad * 8);
    const bf16x8 bq1b = *(const bf16x8*)(qb + ((size_t)n * HW_ + row_gb) * 64 + 32 + quad * 8);

    f32x4 acc_oa[8], acc_ob[8];
#pragma unroll
    for (int i = 0; i < 8; i++) {
        acc_oa[i] = (f32x4){0.f, 0.f, 0.f, 0.f};
        acc_ob[i] = (f32x4){0.f, 0.f, 0.f, 0.f};
    }
    float l_sa = 0.f, l_sb = 0.f;   // in-lane partial of l(q); reduced at end

    const int stg_row = t >> 3, stg_seg = t & 7;
    const int iters = chunk_j / 64;
    int j0 = chunk * chunk_j;

    // software pipeline: prefetch tile 0 into VGPRs
    bf16x8 kr0, kr1, vr0, vr1, vr2, vr3;
    {
        const unsigned short* kp = kb + ((size_t)n * HW_ + j0 + stg_row) * 64 + stg_seg * 8;
        kr0 = *(const bf16x8*)kp;
        kr1 = *(const bf16x8*)(kp + 32 * 64);
        const unsigned short* vp = vtb + ((size_t)n * CC + stg_row) * HW_ + j0 + stg_seg * 8;
        vr0 = *(const bf16x8*)vp;
        vr1 = *(const bf16x8*)(vp + (size_t)32 * HW_);
        vr2 = *(const bf16x8*)(vp + (size_t)64 * HW_);
        vr3 = *(const bf16x8*)(vp + (size_t)96 * HW_);
    }

    for (int it = 0; it < iters; ++it, j0 += 64) {
        __syncthreads();   // previous iteration's k/v_lds reads complete
        {
            int r0 = stg_row, r1 = stg_row + 32;
            *(bf16x8*)&k_lds[r0 * 64 + ((stg_seg ^ (r0 & 7)) * 8)] = kr0;
            *(bf16x8*)&k_lds[r1 * 64 + ((stg_seg ^ (r1 & 7)) * 8)] = kr1;
            *(bf16x8*)&v_lds[r0 * 64 + ((stg_seg ^ (r0 & 7)) * 8)] = vr0;
            *(bf16x8*)&v_lds[r1 * 64 + ((stg_seg ^ (r1 & 7)) * 8)] = vr1;
            int r2 = stg_row + 64, r3 = stg_row + 96;
            *(bf16x8*)&v_lds[r2 * 64 + ((stg_seg ^ (r2 & 7)) * 8)] = vr2;
            *(bf16x8*)&v_lds[r3 * 64 + ((stg_seg ^ (r3 & 7)) * 8)] = vr3;
        }
        __syncthreads();

        if (it + 1 < iters) {   // issue next tile's loads; overlap with compute
            const unsigned short* kp = kb + ((size_t)n * HW_ + j0 + 64 + stg_row) * 64 + stg_seg * 8;
            kr0 = *(const bf16x8*)kp;
            kr1 = *(const bf16x8*)(kp + 32 * 64);
            const unsigned short* vp = vtb + ((size_t)n * CC + stg_row) * HW_ + j0 + 64 + stg_seg * 8;
            vr0 = *(const bf16x8*)vp;
            vr1 = *(const bf16x8*)(vp + (size_t)32 * HW_);
            vr2 = *(const bf16x8*)(vp + (size_t)64 * HW_);
            vr3 = *(const bf16x8*)(vp + (size_t)96 * HW_);
        }

        // S^T = K Q^T: 4 tiles along j (16 each), both q-halves per A-read
        f32x4 sa[4], sb[4];
#pragma unroll
        for (int ct = 0; ct < 4; ct++) {
            int jr = ct * 16 + l15;
            bf16x8 ak0 = *(const bf16x8*)&k_lds[jr * 64 + ((quad ^ e7) * 8)];
            bf16x8 ak1 = *(const bf16x8*)&k_lds[jr * 64 + (((4 + quad) ^ e7) * 8)];
            f32x4 za = (f32x4){0.f, 0.f, 0.f, 0.f};
            za = __builtin_amdgcn_mfma_f32_16x16x32_bf16(ak0, bq0a, za, 0, 0, 0);
            za = __builtin_amdgcn_mfma_f32_16x16x32_bf16(ak1, bq1a, za, 0, 0, 0);
            sa[ct] = za;
            f32x4 zb = (f32x4){0.f, 0.f, 0.f, 0.f};
            zb = __builtin_amdgcn_mfma_f32_16x16x32_bf16(ak0, bq0b, zb, 0, 0, 0);
            zb = __builtin_amdgcn_mfma_f32_16x16x32_bf16(ak1, bq1b, zb, 0, 0, 0);
            sb[ct] = zb;
        }

        // ---- half a: P = exp2(S) raw (no max), in-lane l, pack, stage ----
#pragma unroll
        for (int ct = 0; ct < 4; ct++) {
            sa[ct][0] = fast_exp2(sa[ct][0]);
            sa[ct][1] = fast_exp2(sa[ct][1]);
            sa[ct][2] = fast_exp2(sa[ct][2]);
            sa[ct][3] = fast_exp2(sa[ct][3]);
        }
        {   // explicit pairwise tree (no fast-math reassociation available)
            float u0 = sa[0][0] + sa[0][1], u1 = sa[0][2] + sa[0][3];
            float u2 = sa[1][0] + sa[1][1], u3 = sa[1][2] + sa[1][3];
            float u4 = sa[2][0] + sa[2][1], u5 = sa[2][2] + sa[2][3];
            float u6 = sa[3][0] + sa[3][1], u7 = sa[3][2] + sa[3][3];
            float v0 = u0 + u1, v1 = u2 + u3, v2 = u4 + u5, v3 = u6 + u7;
            l_sa += (v0 + v1) + (v2 + v3);
        }
#pragma unroll
        for (int ct = 0; ct < 4; ct++) {
            unsigned int pk01 = cvt_pk_bf16(sa[ct][0], sa[ct][1]);
            unsigned int pk23 = cvt_pk_bf16(sa[ct][2], sa[ct][3]);
            int chunkid = 2 * ct + (quad >> 1);
            int off = l15 * 64 + ((chunkid ^ e7) * 8) + 4 * (quad & 1);
            uint2 tmp;
            tmp.x = pk01;
            tmp.y = pk23;
            *(u16x4*)&p_lds[w * 1024 + off] = __builtin_bit_cast(u16x4, tmp);
        }
        asm volatile("" ::: "memory");   // writes-a before reads-a
        const bf16x8 bp0a = __builtin_bit_cast(bf16x8,
            *(const u16x8*)&p_lds[w * 1024 + l15 * 64 + ((quad ^ e7) * 8)]);
        const bf16x8 bp1a = __builtin_bit_cast(bf16x8,
            *(const u16x8*)&p_lds[w * 1024 + l15 * 64 + (((4 + quad) ^ e7) * 8)]);
        asm volatile("" ::: "memory");   // reads-a before writes-b (buffer reuse)

        // ---- half b ----
#pragma unroll
        for (int ct = 0; ct < 4; ct++) {
            sb[ct][0] = fast_exp2(sb[ct][0]);
            sb[ct][1] = fast_exp2(sb[ct][1]);
            sb[ct][2] = fast_exp2(sb[ct][2]);
            sb[ct][3] = fast_exp2(sb[ct][3]);
        }
        {
            float u0 = sb[0][0] + sb[0][1], u1 = sb[0][2] + sb[0][3];
            float u2 = sb[1][0] + sb[1][1], u3 = sb[1][2] + sb[1][3];
            float u4 = sb[2][0] + sb[2][1], u5 = sb[2][2] + sb[2][3];
            float u6 = sb[3][0] + sb[3][1], u7 = sb[3][2] + sb[3][3];
            float v0 = u0 + u1, v1 = u2 + u3, v2 = u4 + u5, v3 = u6 + u7;
            l_sb += (v0 + v1) + (v2 + v3);
        }
#pragma unroll
        for (int ct = 0; ct < 4; ct++) {
            unsigned int pk01 = cvt_pk_bf16(sb[ct][0], sb[ct][1]);
            unsigned int pk23 = cvt_pk_bf16(sb[ct][2], sb[ct][3]);
            int chunkid = 2 * ct + (quad >> 1);
            int off = l15 * 64 + ((chunkid ^ e7) * 8) + 4 * (quad & 1);
            uint2 tmp;
            tmp.x = pk01;
            tmp.y = pk23;
            *(u16x4*)&p_lds[w * 1024 + off] = __builtin_bit_cast(u16x4, tmp);
        }
        asm volatile("" ::: "memory");   // writes-b before reads-b
        const bf16x8 bp0b = __builtin_bit_cast(bf16x8,
            *(const u16x8*)&p_lds[w * 1024 + l15 * 64 + ((quad ^ e7) * 8)]);
        const bf16x8 bp1b = __builtin_bit_cast(bf16x8,
            *(const u16x8*)&p_lds[w * 1024 + l15 * 64 + (((4 + quad) ^ e7) * 8)]);
        asm volatile("" ::: "memory");   // reads-b before next iter's writes-a

        // O^T += V^T P^T (both halves share each V A-read)
        __builtin_amdgcn_s_setprio(1);
#pragma unroll
        for (int ctv = 0; ctv < 8; ctv++) {
            int cr = ctv * 16 + l15;
            bf16x8 av0 = *(const bf16x8*)&v_lds[cr * 64 + ((quad ^ e7) * 8)];
            bf16x8 av1 = *(const bf16x8*)&v_lds[cr * 64 + (((4 + quad) ^ e7) * 8)];
            acc_oa[ctv] = __builtin_amdgcn_mfma_f32_16x16x32_bf16(av0, bp0a, acc_oa[ctv], 0, 0, 0);
            acc_oa[ctv] = __builtin_amdgcn_mfma_f32_16x16x32_bf16(av1, bp1a, acc_oa[ctv], 0, 0, 0);
            acc_ob[ctv] = __builtin_amdgcn_mfma_f32_16x16x32_bf16(av0, bp0b, acc_ob[ctv], 0, 0, 0);
            acc_ob[ctv] = __builtin_amdgcn_mfma_f32_16x16x32_bf16(av1, bp1b, acc_ob[ctv], 0, 0, 0);
        }
        __builtin_amdgcn_s_setprio(0);
    }

    // epilogue: reduce l across quads (once per kernel, not per iter)
    l_sa += __shfl_xor(l_sa, 16);
    l_sa += __shfl_xor(l_sa, 32);
    l_sb += __shfl_xor(l_sb, 16);
    l_sb += __shfl_xor(l_sb, 32);

    // partials: O^T layout [c][q], q in [0,128) per block
    const size_t cbase = ((size_t)(n * NQT2 + qt) * nch + chunk) * 128;
    const int qla = w * 32 + l15, qlb = qla + 16;
#pragma unroll
    for (int ctv = 0; ctv < 8; ctv++)
#pragma unroll
        for (int r = 0; r < 4; r++) {
            int c = ctv * 16 + 4 * quad + r;
            o_part[(cbase + c) * 128 + qla] = acc_oa[ctv][r];
            o_part[(cbase + c) * 128 + qlb] = acc_ob[ctv][r];
        }
    if (quad == 0) {   // l is quad-uniform per q after the reduce
        size_t lb = ((size_t)(n * NQT2 + qt) * nch + chunk) * 128;
        l_part[lb + qla] = l_sa;
        l_part[lb + qlb] = l_sb;
    }
}

// ---------------------------------------------------------------------------
// Kernel 4: combine nch partials (plain sums — no max tracking), normalize,
// write out[n][c][p] fp32. float4-vectorized over q (4 q per thread).
// Layout: o_part[((nqt*nch+ch)*128 + c)*128 + q], l[(nqt*nch+ch)*128 + q]
// ---------------------------------------------------------------------------
__global__ __launch_bounds__(256) void combine_kernel(
    const float* __restrict__ o_part, const float* __restrict__ lp,
    float* __restrict__ out, int nch) {
    int gid = blockIdx.x * 256 + threadIdx.x;   // covers (nqt, c, q/4)
    int r4 = (gid & 31) * 4;       // q within block, 4 at a time
    int rest = gid >> 5;
    int c = rest & 127;
    int nqt = rest >> 7;           // 0..143 = n*72 + qtp
    int n = nqt / NQT2, qtp = nqt - n * NQT2;

    float4 num = {0.f, 0.f, 0.f, 0.f}, den = {0.f, 0.f, 0.f, 0.f};
    for (int ch = 0; ch < nch; ch++) {
        float4 o = *(const float4*)&o_part[(((size_t)nqt * nch + ch) * 128 + c) * 128 + r4];
        float4 l = *(const float4*)&lp[((size_t)nqt * nch + ch) * 128 + r4];
        num.x += o.x; num.y += o.y; num.z += o.z; num.w += o.w;
        den.x += l.x; den.y += l.y; den.z += l.z; den.w += l.w;
    }
    float4 res;
    res.x = num.x / den.x;
    res.y = num.y / den.y;
    res.z = num.z / den.z;
    res.w = num.w / den.w;
    *(float4*)&out[((size_t)n * CC + c) * HW_ + qtp * 128 + r4] = res;
}

// ---------------------------------------------------------------------------
// Workspace layout (bytes):
//   wt 0 (131072) | qb 131072 (2359296) | kb 2490368 (2359296)
//   vtb 4849664 (4718592) | o_part 9568256 (nch*9437184) | l after o_part
// l = nch * 73728 bytes. Ladder: nch 6 (~67 MB, R6-proven) -> 4 -> 2.
// (nch=12 was tested in R10: attn flat, combine doubles -> net negative.)
// ---------------------------------------------------------------------------
extern "C" void kernel_launch(void* const* d_in, const int* in_sizes, int n_in,
                              void* d_out, int out_size, void* d_ws, size_t ws_size,
                              hipStream_t stream) {
    const float* x  = (const float*)d_in[0];
    const float* w1 = (const float*)d_in[1];
    const float* b1 = (const float*)d_in[2];
    const float* a1 = (const float*)d_in[3];
    const float* w2 = (const float*)d_in[4];
    const float* b2 = (const float*)d_in[5];
    const float* a2 = (const float*)d_in[6];
    const float* wa = (const float*)d_in[7];
    const float* ba = (const float*)d_in[8];
    const float* aa = (const float*)d_in[9];
    float* out = (float*)d_out;

    auto need = [](int nc) -> size_t {
        return 9568256ull + (size_t)nc * 9437184ull + (size_t)nc * 73728ull;
    };
    int nch;
    if (ws_size >= need(6))      nch = 6;    // R6-proven config
    else if (ws_size >= need(4)) nch = 4;
    else                         nch = 2;
    const int chunk_j = HW_ / nch;

    char* ws = (char*)d_ws;
    float*          wt     = (float*)(ws + 0);
    unsigned short* qb     = (unsigned short*)(ws + 131072);
    unsigned short* kb     = (unsigned short*)(ws + 2490368);
    unsigned short* vtb    = (unsigned short*)(ws + 4849664);
    float*          o_part = (float*)(ws + 9568256);
    float*          lpart  = (float*)(ws + 9568256 + (size_t)nch * 9437184);

    hipLaunchKernelGGL(prep_w, dim3(128), dim3(256), 0, stream, w1, w2, wa, wt);
    hipLaunchKernelGGL(conv_kernel, dim3(144, 4, 2), dim3(256), 0, stream,
                       x, wt, b1, a1, b2, a2, ba, aa, qb, kb, vtb);
    hipLaunchKernelGGL(attn_kernel, dim3(NQT2, nch, 2), dim3(256), 0, stream,
                       qb, kb, vtb, o_part, lpart, nch, chunk_j);
    hipLaunchKernelGGL(combine_kernel, dim3(2 * NQT2 * 128 * 128 / (256 * 4)), dim3(256), 0, stream,
                       o_part, lpart, out, nch);
}